// Round 13
// baseline (337.921 us; speedup 1.0000x reference)
//
#include <hip/hip_runtime.h>
#include <hip/hip_bf16.h>
#include <stdint.h>
#include <stddef.h>

#define DIMV 2048
#define CTXV 512
#define BV   8192
#define NPV  512
#define NSV  256

typedef __attribute__((ext_vector_type(8))) __bf16 bf16x8;
typedef __attribute__((ext_vector_type(4))) __bf16 bf16x4;
typedef __attribute__((ext_vector_type(4))) float f32x4;

// ---------------------------------------------------------------------------
// FM (fragment-major) layout for a [R][K] bf16 matrix, nks = K/32:
//   16B-chunk index q(r, kc) = ((r>>4)*nks + (kc>>2))*64 + (kc&3)*16 + (r&15)
//   (kc = k>>3); byte addr = q*16 + (k&7)*2.
// Wave frag load = base + lane*16 -> perfectly coalesced 1KB. No LDS, no
// barriers in any GEMM.
// ---------------------------------------------------------------------------
__device__ __forceinline__ size_t fmq(int base_r, int Cb, int lhi, int llo, int nks) {
    const int kc = (Cb >> 3) + (lhi >> 1);
    return ((size_t)(base_r >> 4) * nks + (kc >> 2)) * 64 + (size_t)(kc & 3) * 16 + llo;
}

// ---------------------------------------------------------------------------
// fp32 -> FM bf16 converter for 12 matrices (ctx, x, 10 weight views).
// ---------------------------------------------------------------------------
struct FmJob { const float* src; char* dst; int lognks; int ld; int trans; };
struct FmArgs { FmJob j[12]; unsigned cum[13]; };

__global__ __launch_bounds__(256) void cvt_fm(FmArgs a) {
    const unsigned total = a.cum[12];
    for (unsigned c = blockIdx.x * blockDim.x + threadIdx.x; c < total;
         c += gridDim.x * blockDim.x) {
        int seg = 0;
#pragma unroll
        for (int t = 1; t < 12; ++t) seg = (c >= a.cum[t]) ? t : seg;
        const FmJob jb = a.j[seg];
        const unsigned q = c - a.cum[seg];
        const int llo = q & 15, ch = (q >> 4) & 3;
        const unsigned blk = q >> 6;
        const unsigned s = blk & ((1u << jb.lognks) - 1u);
        const unsigned g = blk >> jb.lognks;
        const int row = g * 16 + llo;
        const int k0  = s * 32 + ch * 8;
        bf16x8 o;
        if (!jb.trans) {
            f32x4 v0 = *(const f32x4*)(jb.src + (size_t)row * jb.ld + k0);
            f32x4 v1 = *(const f32x4*)(jb.src + (size_t)row * jb.ld + k0 + 4);
#pragma unroll
            for (int e = 0; e < 4; ++e) { o[e] = (__bf16)v0[e]; o[e + 4] = (__bf16)v1[e]; }
        } else {
#pragma unroll
            for (int e = 0; e < 8; ++e)
                o[e] = (__bf16)jb.src[(size_t)(k0 + e) * jb.ld + row];
        }
        *(bf16x8*)(jb.dst + (size_t)q * 16) = o;
    }
}

// ---------------------------------------------------------------------------
// biascomb[0:512) = Wpv2 @ b_pred ; biascomb[512:768) = Wvip @ b_pred (f32 in)
// ---------------------------------------------------------------------------
__global__ __launch_bounds__(512)
void bias_comb(const float* __restrict__ Wpv2, const float* __restrict__ Wvip,
               const float* __restrict__ b, float* __restrict__ out) {
    const int tid  = threadIdx.x;
    const int gw   = blockIdx.x * 8 + (tid >> 6);
    const int lane = tid & 63;
    const float* row = (gw < 512) ? (Wpv2 + (size_t)gw * 2048)
                                  : (Wvip + (size_t)(gw - 512) * 2048);
    float acc = 0.f;
#pragma unroll
    for (int c = 0; c < 8; ++c) {
        const int j = lane * 32 + c * 4;
        f32x4 w  = *(const f32x4*)(row + j);
        f32x4 bb = *(const f32x4*)(b + j);
#pragma unroll
        for (int e = 0; e < 4; ++e) acc += w[e] * bb[e];
    }
#pragma unroll
    for (int off = 32; off > 0; off >>= 1) acc += __shfl_down(acc, off);
    if (lane == 0) out[gw] = acc;
}

// ---------------------------------------------------------------------------
// LDS-FREE FM GEMM, occupancy-first 8-wave version:
// 128x128 block, 512 threads = 8 waves (4x2), PER-WAVE TILE 32x64
// (acc[2][4] = 32 acc regs, frag dbuf 48 VGPR -> ~100 regs/wave), BK=32,
// register double-buffer, zero barriers.
// Same block geometry / grids as the FETCH-ideal r9 version; only the
// intra-block wave partition changed (more, lighter waves in flight).
// MFMA operands SWAPPED:
//   batch row = m0 + wr*32 + i*16 + (lane&15)          (i < 2, wr = wave>>1)
//   out col   = n0 + wc*64 + j*16 + (lane>>4)*4 + r    [harness-verified]
// ---------------------------------------------------------------------------
#define GEOM8                                                     \
    const int tid  = threadIdx.x;                                 \
    const int wave = tid >> 6;                                    \
    const int lane = tid & 63;                                    \
    const int lhi  = lane >> 4;                                   \
    const int llo  = lane & 15;                                   \
    const int wr   = wave >> 1;   /* 0..3 */                      \
    const int wc   = wave & 1;    /* 0..1 */

#define SETPA(Abase, nksA_)                                                   \
    _Pragma("unroll")                                                         \
    for (int i_ = 0; i_ < 2; ++i_) {                                          \
        const int g_ = (m0 + wr * 32 + i_ * 16) >> 4;                         \
        pa[i_] = (const char*)(Abase) + ((size_t)g_ * (nksA_)) * 1024 + lane * 16; \
    }
#define SETPW(Wbase, nksW_, nbase)                                            \
    _Pragma("unroll")                                                         \
    for (int j_ = 0; j_ < 4; ++j_) {                                          \
        const int g_ = ((nbase) + wc * 64 + j_ * 16) >> 4;                    \
        pw[j_] = (const char*)(Wbase) + ((size_t)g_ * (nksW_)) * 1024 + lane * 16; \
    }
#define LD6(AF, BF, OFS)                                                      \
    _Pragma("unroll")                                                         \
    for (int i_ = 0; i_ < 2; ++i_) AF[i_] = *(const bf16x8*)(pa[i_] + (OFS)); \
    _Pragma("unroll")                                                         \
    for (int j_ = 0; j_ < 4; ++j_) BF[j_] = *(const bf16x8*)(pw[j_] + (OFS));
#define ADV2                                                                  \
    _Pragma("unroll")                                                         \
    for (int i_ = 0; i_ < 2; ++i_) pa[i_] += 2048;                            \
    _Pragma("unroll")                                                         \
    for (int j_ = 0; j_ < 4; ++j_) pw[j_] += 2048;
#define MFMA8(af, bfr, acc)                                                   \
    __builtin_amdgcn_s_setprio(1);                                            \
    _Pragma("unroll")                                                         \
    for (int i = 0; i < 2; ++i)                                               \
        _Pragma("unroll")                                                     \
        for (int j = 0; j < 4; ++j)                                           \
            acc[i][j] = __builtin_amdgcn_mfma_f32_16x16x32_bf16(bfr[j], af[i], acc[i][j], 0, 0, 0); \
    __builtin_amdgcn_s_setprio(0);

struct GemmDesc {
    const char* A; int nksA;
    const char* W1; const char* W2; int nksW;
    int NB1, ntN, nsteps, epi;   // epi: 0 diff(x-(acc+bias)), 1 relu-region, 2 subr, 3 plain, 4 bias768+relu-region
    const float* bias;
    const char* subp; int nksSub;   // epi=0: x_fm ; epi=2: ssom_fm
    char* out1; int nksO1; char* out2; int nksO2;
};

__global__ __launch_bounds__(512, 3)
void pe_gemm9(GemmDesc dA_, GemmDesc dB_, GemmDesc dC_, int s1, int s2)
{
    const int nwg = gridDim.x;
    const int bid = blockIdx.x;
    int wg = (bid & 7) * (nwg >> 3) + (bid >> 3);   // XCD-bijective (nwg%8==0)
    GemmDesc d = dA_;
    if (wg >= s2)      { d = dC_; wg -= s2; }
    else if (wg >= s1) { d = dB_; wg -= s1; }
    if (d.out1 == nullptr) return;

    const int bx = wg / d.ntN;           // A-panel-major
    const int by = wg - bx * d.ntN;
    const int m0 = bx * 128;
    const int n0 = by * 128;

    const bool reg2  = (d.W2 != nullptr) && (n0 >= d.NB1);
    const char* Wc   = reg2 ? d.W2 : d.W1;
    const int n0r    = reg2 ? (n0 - d.NB1) : n0;

    GEOM8

    const f32x4 fzero = {0.f, 0.f, 0.f, 0.f};
    f32x4 acc[2][4];
#pragma unroll
    for (int i = 0; i < 2; ++i)
#pragma unroll
        for (int j = 0; j < 4; ++j) acc[i][j] = fzero;

    const char* pa[2]; const char* pw[4];
    SETPA(d.A, d.nksA)
    SETPW(Wc, d.nksW, n0r)

    bf16x8 A0[2], B0[4], A1[2], B1[4];
    LD6(A0, B0, 0)
    const int half = d.nsteps >> 1;      // nsteps always even here
    for (int it = 0; it < half; ++it) {
        LD6(A1, B1, 1024)
        MFMA8(A0, B0, acc)
        ADV2
        if (it + 1 < half) { LD6(A0, B0, 0) }
        MFMA8(A1, B1, acc)
    }

#pragma unroll
    for (int i = 0; i < 2; ++i) {
#pragma unroll
        for (int j = 0; j < 4; ++j) {
            const int base_r = m0 + wr * 32 + i * 16;
            const int CbL    = (reg2 ? n0r : n0) + wc * 64 + j * 16;  // region-local
            if (d.epi == 0) {            // diff = x - (acc + bias) -> FM bf16
                const int colg = n0 + wc * 64 + j * 16 + lhi * 4;
                f32x4 b4 = *(const f32x4*)(d.bias + colg);
                bf16x4 xb = *(const bf16x4*)(d.subp + fmq(base_r, CbL, lhi, llo, d.nksSub) * 16 + (lhi & 1) * 8);
                bf16x4 o;
#pragma unroll
                for (int r = 0; r < 4; ++r)
                    o[r] = (__bf16)((float)xb[r] - (acc[i][j][r] + b4[r]));
                *(bf16x4*)(d.out1 + fmq(base_r, CbL, lhi, llo, d.nksO1) * 16 + (lhi & 1) * 8) = o;
            } else if (d.epi == 1) {     // relu -> FM bf16, N-region
                char* op     = reg2 ? d.out2 : d.out1;
                const int nk = reg2 ? d.nksO2 : d.nksO1;
                bf16x4 o;
#pragma unroll
                for (int r = 0; r < 4; ++r) o[r] = (__bf16)fmaxf(acc[i][j][r], 0.f);
                *(bf16x4*)(op + fmq(base_r, CbL, lhi, llo, nk) * 16 + (lhi & 1) * 8) = o;
            } else if (d.epi == 2) {     // relu(subp - acc) -> FM bf16
                bf16x4 s4 = *(const bf16x4*)(d.subp + fmq(base_r, CbL, lhi, llo, d.nksSub) * 16 + (lhi & 1) * 8);
                bf16x4 o;
#pragma unroll
                for (int r = 0; r < 4; ++r)
                    o[r] = (__bf16)fmaxf((float)s4[r] - acc[i][j][r], 0.f);
                *(bf16x4*)(d.out1 + fmq(base_r, CbL, lhi, llo, d.nksO1) * 16 + (lhi & 1) * 8) = o;
            } else if (d.epi == 3) {     // plain -> FM bf16 (Wcomb)
                bf16x4 o;
#pragma unroll
                for (int r = 0; r < 4; ++r) o[r] = (__bf16)acc[i][j][r];
                *(bf16x4*)(d.out1 + fmq(base_r, CbL, lhi, llo, d.nksO1) * 16 + (lhi & 1) * 8) = o;
            } else {                     // bias768 + relu -> FM bf16, N-region
                const int colg = n0 + wc * 64 + j * 16 + lhi * 4;
                f32x4 b4 = *(const f32x4*)(d.bias + colg);
                char* op     = reg2 ? d.out2 : d.out1;
                const int nk = reg2 ? d.nksO2 : d.nksO1;
                bf16x4 o;
#pragma unroll
                for (int r = 0; r < 4; ++r)
                    o[r] = (__bf16)fmaxf(acc[i][j][r] + b4[r], 0.f);
                *(bf16x4*)(op + fmq(base_r, CbL, lhi, llo, nk) * 16 + (lhi & 1) * 8) = o;
            }
        }
    }
}

// ---------------------------------------------------------------------------
// Merged FILT (steps 7+8), LDS-free FM, barrier-free, 8-wave 128x128 blocks.
//   out_pos = 0.9*r_pos + 0.1*relu( diff - rpv2 @ Wpepos^T)
//   out_neg = 0.9*r_neg + 0.1*relu(-diff - rpv1 @ Wpeneg^T - rsom @ Wsomd^T)
// diff = x - pred precomputed (FM bf16, nks=64); single 32MB stream instead
// of x+pred. First NEG loads issued before the POS epilogue.
// ---------------------------------------------------------------------------
__global__ __launch_bounds__(512, 3)
void pe_filt9(const char* __restrict__ rpv2f, const char* __restrict__ Wposf,
              const char* __restrict__ rpv1f, const char* __restrict__ rsomf,
              const char* __restrict__ Wneg1f, const char* __restrict__ Wneg2f,
              const char* __restrict__ difff,
              const float* __restrict__ rpos, const float* __restrict__ rneg,
              float* __restrict__ outp, float* __restrict__ outn)
{
    const int nwg = gridDim.x;
    const int bid = blockIdx.x;
    const int wg  = (bid & 7) * (nwg >> 3) + (bid >> 3);
    const int bx  = wg >> 4;          // panel-major, 16 n-tiles
    const int by  = wg & 15;
    const int m0  = bx * 128;
    const int n0  = by * 128;

    GEOM8

    const f32x4 fzero = {0.f, 0.f, 0.f, 0.f};
    f32x4 acc[2][4];
#pragma unroll
    for (int i = 0; i < 2; ++i)
#pragma unroll
        for (int j = 0; j < 4; ++j) acc[i][j] = fzero;

    const char* pa[2]; const char* pw[4];
    bf16x8 A0[2], B0[4], A1[2], B1[4];

    // ---- POS: K=512, nks=16, 16 steps = 8 iters ----
    SETPA(rpv2f, 16)
    SETPW(Wposf, 16, n0)
    LD6(A0, B0, 0)
    for (int it = 0; it < 8; ++it) {
        LD6(A1, B1, 1024)
        MFMA8(A0, B0, acc)
        ADV2
        if (it + 1 < 8) { LD6(A0, B0, 0) }
        MFMA8(A1, B1, acc)
    }
    // issue first NEG loads now; they land under the POS epilogue
    SETPA(rpv1f, 16)
    SETPW(Wneg1f, 16, n0)
    LD6(A0, B0, 0)

    // ---- POS epilogue ----
#pragma unroll
    for (int i = 0; i < 2; ++i) {
#pragma unroll
        for (int j = 0; j < 4; ++j) {
            const int base_r = m0 + wr * 32 + i * 16;
            const int Cb     = n0 + wc * 64 + j * 16;
            const int rowg   = base_r + llo;
            const int colg   = Cb + lhi * 4;
            const size_t idx = (size_t)rowg * 2048 + colg;
            const size_t qx  = fmq(base_r, Cb, lhi, llo, 64) * 16 + (lhi & 1) * 8;
            f32x4 rp  = *(const f32x4*)(rpos + idx);
            bf16x4 db = *(const bf16x4*)(difff + qx);
            f32x4 o;
#pragma unroll
            for (int r = 0; r < 4; ++r)
                o[r] = 0.9f * rp[r] + 0.1f * fmaxf((float)db[r] - acc[i][j][r], 0.f);
            *(f32x4*)(outp + idx) = o;
            acc[i][j] = fzero;
        }
    }

    // ---- NEG part 1: rpv1/Wpeneg, 16 steps (step-0 loads already in flight) ----
    for (int it = 0; it < 8; ++it) {
        LD6(A1, B1, 1024)
        MFMA8(A0, B0, acc)
        ADV2
        if (it + 1 < 8) { LD6(A0, B0, 0) }
        MFMA8(A1, B1, acc)
    }
    // ---- NEG part 2: rsom/Wsomd, nks=8, 8 steps = 4 iters ----
    SETPA(rsomf, 8)
    SETPW(Wneg2f, 8, n0)
    LD6(A0, B0, 0)
    for (int it = 0; it < 4; ++it) {
        LD6(A1, B1, 1024)
        MFMA8(A0, B0, acc)
        ADV2
        if (it + 1 < 4) { LD6(A0, B0, 0) }
        MFMA8(A1, B1, acc)
    }

    // ---- NEG epilogue ----
#pragma unroll
    for (int i = 0; i < 2; ++i) {
#pragma unroll
        for (int j = 0; j < 4; ++j) {
            const int base_r = m0 + wr * 32 + i * 16;
            const int Cb     = n0 + wc * 64 + j * 16;
            const int rowg   = base_r + llo;
            const int colg   = Cb + lhi * 4;
            const size_t idx = (size_t)rowg * 2048 + colg;
            const size_t qx  = fmq(base_r, Cb, lhi, llo, 64) * 16 + (lhi & 1) * 8;
            f32x4 rn  = *(const f32x4*)(rneg + idx);
            bf16x4 db = *(const bf16x4*)(difff + qx);
            f32x4 o;
#pragma unroll
            for (int r = 0; r < 4; ++r)
                o[r] = 0.9f * rn[r] + 0.1f * fmaxf(-(float)db[r] - acc[i][j][r], 0.f);
            *(f32x4*)(outn + idx) = o;
        }
    }
}

extern "C" void kernel_launch(void* const* d_in, const int* in_sizes, int n_in,
                              void* d_out, int out_size, void* d_ws, size_t ws_size,
                              hipStream_t stream) {
    (void)in_sizes; (void)n_in; (void)out_size; (void)ws_size;

    const float* x       = (const float*)d_in[0];
    const float* ctx     = (const float*)d_in[1];
    const float* r_pos   = (const float*)d_in[2];
    const float* r_neg   = (const float*)d_in[3];
    const float* Wpred   = (const float*)d_in[4];
    const float* bpred   = (const float*)d_in[5];
    const float* Wpv1    = (const float*)d_in[6];
    const float* Wpv2    = (const float*)d_in[7];
    const float* Wvip    = (const float*)d_in[8];
    const float* Wsomin  = (const float*)d_in[9];
    const float* Wvipsom = (const float*)d_in[10];
    const float* Wpepos  = (const float*)d_in[11];
    const float* Wpeneg  = (const float*)d_in[12];
    const float* Wsomd   = (const float*)d_in[13];

    char* ws = (char*)d_ws;
    char* ctx_fm     = ws; ws += (size_t)BV * CTXV * 2;
    char* x_fm       = ws; ws += (size_t)BV * DIMV * 2;
    char* diff_fm    = ws; ws += (size_t)BV * DIMV * 2;
    char* rpv1_fm    = ws; ws += (size_t)BV * NPV * 2;
    char* rpv2_fm    = ws; ws += (size_t)BV * NPV * 2;
    char* rvip_fm    = ws; ws += (size_t)BV * NSV * 2;
    char* ssom_fm    = ws; ws += (size_t)BV * NSV * 2;
    char* rsom_fm    = ws; ws += (size_t)BV * NSV * 2;
    char* Wpred_fm   = ws; ws += (size_t)DIMV * CTXV * 2;
    char* WpredT_fm  = ws; ws += (size_t)CTXV * DIMV * 2;
    char* Wpv1_fm    = ws; ws += (size_t)NPV * DIMV * 2;
    char* Wpv2_fm    = ws; ws += (size_t)NPV * DIMV * 2;
    char* Wvip_fm    = ws; ws += (size_t)NSV * DIMV * 2;
    char* Wsomin_fm  = ws; ws += (size_t)NSV * DIMV * 2;
    char* Wvipsom_fm = ws; ws += (size_t)NSV * NSV * 2;
    char* Wpepos_fm  = ws; ws += (size_t)DIMV * NPV * 2;
    char* Wpeneg_fm  = ws; ws += (size_t)DIMV * NPV * 2;
    char* Wsomd_fm   = ws; ws += (size_t)DIMV * NSV * 2;
    char* Wcomb2_fm  = ws; ws += (size_t)NPV * CTXV * 2;
    char* Wcombv_fm  = ws; ws += (size_t)NSV * CTXV * 2;
    float* biascomb  = (float*)ws; ws += 768 * 4;

    float* out_pos = (float*)d_out;
    float* out_neg = out_pos + (size_t)BV * DIMV;

    // ---- FM conversions (12 jobs) ----
    FmArgs fa;
    auto setj = [&](int t, const float* s, char* dst, int lognks, int ld, int trans) {
        fa.j[t].src = s; fa.j[t].dst = dst; fa.j[t].lognks = lognks;
        fa.j[t].ld = ld; fa.j[t].trans = trans;
    };
    setj(0,  ctx,     ctx_fm,     4, 512,  0);
    setj(1,  x,       x_fm,       6, 2048, 0);
    setj(2,  Wpred,   Wpred_fm,   4, 512,  0);
    setj(3,  Wpred,   WpredT_fm,  6, 512,  1);   // WpredT[r][k] = Wpred[k][r]
    setj(4,  Wpv1,    Wpv1_fm,    6, 2048, 0);
    setj(5,  Wpv2,    Wpv2_fm,    6, 2048, 0);
    setj(6,  Wvip,    Wvip_fm,    6, 2048, 0);
    setj(7,  Wsomin,  Wsomin_fm,  6, 2048, 0);
    setj(8,  Wvipsom, Wvipsom_fm, 3, 256,  0);
    setj(9,  Wpepos,  Wpepos_fm,  4, 512,  0);
    setj(10, Wpeneg,  Wpeneg_fm,  4, 512,  0);
    setj(11, Wsomd,   Wsomd_fm,   3, 256,  0);
    const unsigned cum[13] = {0u, 524288u, 2621440u, 2752512u, 2883584u,
                              3014656u, 3145728u, 3211264u, 3276800u,
                              3284992u, 3416064u, 3547136u, 3612672u};
    for (int t = 0; t < 13; ++t) fa.cum[t] = cum[t];
    cvt_fm<<<dim3(2048), dim3(256), 0, stream>>>(fa);
    bias_comb<<<dim3(96), dim3(512), 0, stream>>>(Wpv2, Wvip, bpred, biascomb);

    const int BIG = 1 << 28;
    GemmDesc dz;
    dz.A = nullptr; dz.nksA = 1; dz.W1 = dz.W2 = nullptr; dz.nksW = 1;
    dz.NB1 = BIG; dz.ntN = 1; dz.nsteps = 2; dz.epi = 3;
    dz.bias = nullptr; dz.subp = nullptr; dz.nksSub = 1;
    dz.out1 = nullptr; dz.nksO1 = 1; dz.out2 = nullptr; dz.nksO2 = 1;

    // L2: diff=x-pred (1024 blocks) || Wcomb2 (16) || Wcombv (8)
    GemmDesc d_pred = dz;
    d_pred.A = ctx_fm; d_pred.nksA = 16;
    d_pred.W1 = Wpred_fm; d_pred.nksW = 16;
    d_pred.ntN = 16; d_pred.nsteps = 16; d_pred.epi = 0;
    d_pred.bias = bpred;
    d_pred.subp = x_fm; d_pred.nksSub = 64;       // x for diff
    d_pred.out1 = diff_fm; d_pred.nksO1 = 64;

    GemmDesc d_c2 = dz;
    d_c2.A = Wpv2_fm; d_c2.nksA = 64;
    d_c2.W1 = WpredT_fm; d_c2.nksW = 64;
    d_c2.ntN = 4; d_c2.nsteps = 64; d_c2.epi = 3;
    d_c2.out1 = Wcomb2_fm; d_c2.nksO1 = 16;

    GemmDesc d_cv = d_c2;
    d_cv.A = Wvip_fm;
    d_cv.out1 = Wcombv_fm; d_cv.nksO1 = 16;

    pe_gemm9<<<dim3(1048), dim3(512), 0, stream>>>(d_pred, d_c2, d_cv, 1024, 1040);

    // L3: 2+3 (384) || 4'+5' (384)
    GemmDesc d_23 = dz;
    d_23.A = x_fm; d_23.nksA = 64;
    d_23.W1 = Wpv1_fm; d_23.W2 = Wsomin_fm; d_23.nksW = 64;
    d_23.NB1 = NPV; d_23.ntN = 6; d_23.nsteps = 64; d_23.epi = 1;
    d_23.out1 = rpv1_fm; d_23.nksO1 = 16;
    d_23.out2 = ssom_fm; d_23.nksO2 = 8;

    GemmDesc d_45 = dz;
    d_45.A = ctx_fm; d_45.nksA = 16;
    d_45.W1 = Wcomb2_fm; d_45.W2 = Wcombv_fm; d_45.nksW = 16;
    d_45.NB1 = NPV; d_45.ntN = 6; d_45.nsteps = 16; d_45.epi = 4;
    d_45.bias = biascomb;
    d_45.out1 = rpv2_fm; d_45.nksO1 = 16;
    d_45.out2 = rvip_fm; d_45.nksO2 = 8;

    pe_gemm9<<<dim3(768), dim3(512), 0, stream>>>(d_23, d_45, dz, 384, 768);

    // L4: rsom = relu(ssom - rvip @ Wvipsom^T)  (128 blocks)
    GemmDesc d_som = dz;
    d_som.A = rvip_fm; d_som.nksA = 8;
    d_som.W1 = Wvipsom_fm; d_som.nksW = 8;
    d_som.ntN = 2; d_som.nsteps = 8; d_som.epi = 2;
    d_som.subp = ssom_fm; d_som.nksSub = 8;
    d_som.out1 = rsom_fm; d_som.nksO1 = 8;

    pe_gemm9<<<dim3(128), dim3(512), 0, stream>>>(d_som, d_som, d_som, 128, 128);

    // L5: merged FILT (1024 blocks)
    pe_filt9<<<dim3(1024), dim3(512), 0, stream>>>(
        rpv2_fm, Wpepos_fm, rpv1_fm, rsom_fm, Wpeneg_fm, Wsomd_fm,
        diff_fm, r_pos, r_neg, out_pos, out_neg);
}

// Round 14
// 287.153 us; speedup vs baseline: 1.1768x; 1.1768x over previous
//
#include <hip/hip_runtime.h>
#include <hip/hip_bf16.h>
#include <stdint.h>
#include <stddef.h>

#define DIMV 2048
#define CTXV 512
#define BV   8192
#define NPV  512
#define NSV  256

typedef __attribute__((ext_vector_type(8))) __bf16 bf16x8;
typedef __attribute__((ext_vector_type(4))) __bf16 bf16x4;
typedef __attribute__((ext_vector_type(4))) float f32x4;

// ---------------------------------------------------------------------------
// FM (fragment-major) layout for a [R][K] bf16 matrix, nks = K/32:
//   16B-chunk index q(r, kc) = ((r>>4)*nks + (kc>>2))*64 + (kc&3)*16 + (r&15)
//   (kc = k>>3); byte addr = q*16 + (k&7)*2.
// Wave frag load = base + lane*16 -> perfectly coalesced 1KB. No LDS, no
// barriers in any GEMM.  (r9 structure — best measured: 290 us total.)
// ---------------------------------------------------------------------------
__device__ __forceinline__ size_t fmq(int base_r, int Cb, int lhi, int llo, int nks) {
    const int kc = (Cb >> 3) + (lhi >> 1);
    return ((size_t)(base_r >> 4) * nks + (kc >> 2)) * 64 + (size_t)(kc & 3) * 16 + llo;
}

// ---------------------------------------------------------------------------
// fp32 -> FM bf16 converter for 12 matrices (ctx, x, 10 weight views).
// ---------------------------------------------------------------------------
struct FmJob { const float* src; char* dst; int lognks; int ld; int trans; };
struct FmArgs { FmJob j[12]; unsigned cum[13]; };

__global__ __launch_bounds__(256) void cvt_fm(FmArgs a) {
    const unsigned total = a.cum[12];
    for (unsigned c = blockIdx.x * blockDim.x + threadIdx.x; c < total;
         c += gridDim.x * blockDim.x) {
        int seg = 0;
#pragma unroll
        for (int t = 1; t < 12; ++t) seg = (c >= a.cum[t]) ? t : seg;
        const FmJob jb = a.j[seg];
        const unsigned q = c - a.cum[seg];
        const int llo = q & 15, ch = (q >> 4) & 3;
        const unsigned blk = q >> 6;
        const unsigned s = blk & ((1u << jb.lognks) - 1u);
        const unsigned g = blk >> jb.lognks;
        const int row = g * 16 + llo;
        const int k0  = s * 32 + ch * 8;
        bf16x8 o;
        if (!jb.trans) {
            f32x4 v0 = *(const f32x4*)(jb.src + (size_t)row * jb.ld + k0);
            f32x4 v1 = *(const f32x4*)(jb.src + (size_t)row * jb.ld + k0 + 4);
#pragma unroll
            for (int e = 0; e < 4; ++e) { o[e] = (__bf16)v0[e]; o[e + 4] = (__bf16)v1[e]; }
        } else {
#pragma unroll
            for (int e = 0; e < 8; ++e)
                o[e] = (__bf16)jb.src[(size_t)(k0 + e) * jb.ld + row];
        }
        *(bf16x8*)(jb.dst + (size_t)q * 16) = o;
    }
}

// ---------------------------------------------------------------------------
// biascomb[0:512) = Wpv2 @ b_pred ; biascomb[512:768) = Wvip @ b_pred (f32 in)
// ---------------------------------------------------------------------------
__global__ __launch_bounds__(512)
void bias_comb(const float* __restrict__ Wpv2, const float* __restrict__ Wvip,
               const float* __restrict__ b, float* __restrict__ out) {
    const int tid  = threadIdx.x;
    const int gw   = blockIdx.x * 8 + (tid >> 6);
    const int lane = tid & 63;
    const float* row = (gw < 512) ? (Wpv2 + (size_t)gw * 2048)
                                  : (Wvip + (size_t)(gw - 512) * 2048);
    float acc = 0.f;
#pragma unroll
    for (int c = 0; c < 8; ++c) {
        const int j = lane * 32 + c * 4;
        f32x4 w  = *(const f32x4*)(row + j);
        f32x4 bb = *(const f32x4*)(b + j);
#pragma unroll
        for (int e = 0; e < 4; ++e) acc += w[e] * bb[e];
    }
#pragma unroll
    for (int off = 32; off > 0; off >>= 1) acc += __shfl_down(acc, off);
    if (lane == 0) out[gw] = acc;
}

// ---------------------------------------------------------------------------
// LDS-FREE FM GEMM (r9 geometry): 128x128 block, 4 free-running waves
// (2x2 of 64x64), BK=32, 16x16x32 MFMA, register double-buffer, zero
// barriers. MFMA operands SWAPPED:
//   batch row = m0 + wr*64 + i*16 + (lane&15)
//   out col   = n0 + wc*64 + j*16 + (lane>>4)*4 + r     [harness-verified]
// ---------------------------------------------------------------------------
#define GEOM4                                                     \
    const int tid  = threadIdx.x;                                 \
    const int wave = tid >> 6;                                    \
    const int lane = tid & 63;                                    \
    const int lhi  = lane >> 4;                                   \
    const int llo  = lane & 15;                                   \
    const int wr   = wave >> 1;                                   \
    const int wc   = wave & 1;

#define SETPA(Abase, nksA_)                                                   \
    _Pragma("unroll")                                                         \
    for (int i_ = 0; i_ < 4; ++i_) {                                          \
        const int g_ = (m0 + wr * 64 + i_ * 16) >> 4;                         \
        pa[i_] = (const char*)(Abase) + ((size_t)g_ * (nksA_)) * 1024 + lane * 16; \
    }
#define SETPW(Wbase, nksW_, nbase)                                            \
    _Pragma("unroll")                                                         \
    for (int j_ = 0; j_ < 4; ++j_) {                                          \
        const int g_ = ((nbase) + wc * 64 + j_ * 16) >> 4;                    \
        pw[j_] = (const char*)(Wbase) + ((size_t)g_ * (nksW_)) * 1024 + lane * 16; \
    }
#define LD8(AF, BF, OFS)                                                      \
    _Pragma("unroll")                                                         \
    for (int i_ = 0; i_ < 4; ++i_) AF[i_] = *(const bf16x8*)(pa[i_] + (OFS)); \
    _Pragma("unroll")                                                         \
    for (int j_ = 0; j_ < 4; ++j_) BF[j_] = *(const bf16x8*)(pw[j_] + (OFS));
#define ADV2                                                                  \
    _Pragma("unroll")                                                         \
    for (int i_ = 0; i_ < 4; ++i_) pa[i_] += 2048;                            \
    _Pragma("unroll")                                                         \
    for (int j_ = 0; j_ < 4; ++j_) pw[j_] += 2048;
#define MFMA16(af, bfr, acc)                                                  \
    __builtin_amdgcn_s_setprio(1);                                            \
    _Pragma("unroll")                                                         \
    for (int i = 0; i < 4; ++i)                                               \
        _Pragma("unroll")                                                     \
        for (int j = 0; j < 4; ++j)                                           \
            acc[i][j] = __builtin_amdgcn_mfma_f32_16x16x32_bf16(bfr[j], af[i], acc[i][j], 0, 0, 0); \
    __builtin_amdgcn_s_setprio(0);

struct GemmDesc {
    const char* A; int nksA;
    const char* W1; const char* W2; int nksW;
    int NB1, ntN, nsteps, epi;   // epi: 0 diff(x-(acc+bias)), 1 relu-region, 2 subr, 3 plain, 4 bias768+relu-region
    const float* bias;
    const char* subp; int nksSub;   // epi=0: x_fm ; epi=2: ssom_fm
    char* out1; int nksO1; char* out2; int nksO2;
};

__global__ __launch_bounds__(256)
void pe_gemm6(GemmDesc dA_, GemmDesc dB_, GemmDesc dC_, int s1, int s2)
{
    const int nwg = gridDim.x;
    const int bid = blockIdx.x;
    int wg = (bid & 7) * (nwg >> 3) + (bid >> 3);   // XCD-bijective (nwg%8==0)
    GemmDesc d = dA_;
    if (wg >= s2)      { d = dC_; wg -= s2; }
    else if (wg >= s1) { d = dB_; wg -= s1; }
    if (d.out1 == nullptr) return;

    const int bx = wg / d.ntN;           // A-panel-major
    const int by = wg - bx * d.ntN;
    const int m0 = bx * 128;
    const int n0 = by * 128;

    const bool reg2  = (d.W2 != nullptr) && (n0 >= d.NB1);
    const char* Wc   = reg2 ? d.W2 : d.W1;
    const int n0r    = reg2 ? (n0 - d.NB1) : n0;

    GEOM4

    const f32x4 fzero = {0.f, 0.f, 0.f, 0.f};
    f32x4 acc[4][4];
#pragma unroll
    for (int i = 0; i < 4; ++i)
#pragma unroll
        for (int j = 0; j < 4; ++j) acc[i][j] = fzero;

    const char* pa[4]; const char* pw[4];
    SETPA(d.A, d.nksA)
    SETPW(Wc, d.nksW, n0r)

    bf16x8 A0[4], B0[4], A1[4], B1[4];
    LD8(A0, B0, 0)
    const int half = d.nsteps >> 1;      // nsteps always even here
    for (int it = 0; it < half; ++it) {
        LD8(A1, B1, 1024)
        MFMA16(A0, B0, acc)
        ADV2
        if (it + 1 < half) { LD8(A0, B0, 0) }
        MFMA16(A1, B1, acc)
    }

#pragma unroll
    for (int i = 0; i < 4; ++i) {
#pragma unroll
        for (int j = 0; j < 4; ++j) {
            const int base_r = m0 + wr * 64 + i * 16;
            const int CbL    = (reg2 ? n0r : n0) + wc * 64 + j * 16;  // region-local
            if (d.epi == 0) {            // diff = x - (acc + bias) -> FM bf16
                const int colg = n0 + wc * 64 + j * 16 + lhi * 4;
                f32x4 b4 = *(const f32x4*)(d.bias + colg);
                bf16x4 xb = *(const bf16x4*)(d.subp + fmq(base_r, CbL, lhi, llo, d.nksSub) * 16 + (lhi & 1) * 8);
                bf16x4 o;
#pragma unroll
                for (int r = 0; r < 4; ++r)
                    o[r] = (__bf16)((float)xb[r] - (acc[i][j][r] + b4[r]));
                *(bf16x4*)(d.out1 + fmq(base_r, CbL, lhi, llo, d.nksO1) * 16 + (lhi & 1) * 8) = o;
            } else if (d.epi == 1) {     // relu -> FM bf16, N-region
                char* op     = reg2 ? d.out2 : d.out1;
                const int nk = reg2 ? d.nksO2 : d.nksO1;
                bf16x4 o;
#pragma unroll
                for (int r = 0; r < 4; ++r) o[r] = (__bf16)fmaxf(acc[i][j][r], 0.f);
                *(bf16x4*)(op + fmq(base_r, CbL, lhi, llo, nk) * 16 + (lhi & 1) * 8) = o;
            } else if (d.epi == 2) {     // relu(subp - acc) -> FM bf16
                bf16x4 s4 = *(const bf16x4*)(d.subp + fmq(base_r, CbL, lhi, llo, d.nksSub) * 16 + (lhi & 1) * 8);
                bf16x4 o;
#pragma unroll
                for (int r = 0; r < 4; ++r)
                    o[r] = (__bf16)fmaxf((float)s4[r] - acc[i][j][r], 0.f);
                *(bf16x4*)(d.out1 + fmq(base_r, CbL, lhi, llo, d.nksO1) * 16 + (lhi & 1) * 8) = o;
            } else if (d.epi == 3) {     // plain -> FM bf16 (Wcomb)
                bf16x4 o;
#pragma unroll
                for (int r = 0; r < 4; ++r) o[r] = (__bf16)acc[i][j][r];
                *(bf16x4*)(d.out1 + fmq(base_r, CbL, lhi, llo, d.nksO1) * 16 + (lhi & 1) * 8) = o;
            } else {                     // bias768 + relu -> FM bf16, N-region
                const int colg = n0 + wc * 64 + j * 16 + lhi * 4;
                f32x4 b4 = *(const f32x4*)(d.bias + colg);
                char* op     = reg2 ? d.out2 : d.out1;
                const int nk = reg2 ? d.nksO2 : d.nksO1;
                bf16x4 o;
#pragma unroll
                for (int r = 0; r < 4; ++r)
                    o[r] = (__bf16)fmaxf(acc[i][j][r] + b4[r], 0.f);
                *(bf16x4*)(op + fmq(base_r, CbL, lhi, llo, nk) * 16 + (lhi & 1) * 8) = o;
            }
        }
    }
}

// ---------------------------------------------------------------------------
// Merged FILT (steps 7+8), LDS-free FM, barrier-free, r9 geometry + diff:
//   out_pos = 0.9*r_pos + 0.1*relu( diff - rpv2 @ Wpepos^T)
//   out_neg = 0.9*r_neg + 0.1*relu(-diff - rpv1 @ Wpeneg^T - rsom @ Wsomd^T)
// diff = x - pred precomputed (FM bf16, nks=64): one 32MB stream instead of
// x+pred. First NEG loads issued before the POS epilogue.
// ---------------------------------------------------------------------------
__global__ __launch_bounds__(256)
void pe_filt6(const char* __restrict__ rpv2f, const char* __restrict__ Wposf,
              const char* __restrict__ rpv1f, const char* __restrict__ rsomf,
              const char* __restrict__ Wneg1f, const char* __restrict__ Wneg2f,
              const char* __restrict__ difff,
              const float* __restrict__ rpos, const float* __restrict__ rneg,
              float* __restrict__ outp, float* __restrict__ outn)
{
    const int nwg = gridDim.x;
    const int bid = blockIdx.x;
    const int wg  = (bid & 7) * (nwg >> 3) + (bid >> 3);
    const int bx  = wg >> 4;          // panel-major, 16 n-tiles
    const int by  = wg & 15;
    const int m0  = bx * 128;
    const int n0  = by * 128;

    GEOM4

    const f32x4 fzero = {0.f, 0.f, 0.f, 0.f};
    f32x4 acc[4][4];
#pragma unroll
    for (int i = 0; i < 4; ++i)
#pragma unroll
        for (int j = 0; j < 4; ++j) acc[i][j] = fzero;

    const char* pa[4]; const char* pw[4];
    bf16x8 A0[4], B0[4], A1[4], B1[4];

    // ---- POS: K=512, nks=16, 16 steps = 8 iters ----
    SETPA(rpv2f, 16)
    SETPW(Wposf, 16, n0)
    LD8(A0, B0, 0)
    for (int it = 0; it < 8; ++it) {
        LD8(A1, B1, 1024)
        MFMA16(A0, B0, acc)
        ADV2
        if (it + 1 < 8) { LD8(A0, B0, 0) }
        MFMA16(A1, B1, acc)
    }
    // issue first NEG loads now; they land under the POS epilogue
    SETPA(rpv1f, 16)
    SETPW(Wneg1f, 16, n0)
    LD8(A0, B0, 0)

    // ---- POS epilogue ----
#pragma unroll
    for (int i = 0; i < 4; ++i) {
#pragma unroll
        for (int j = 0; j < 4; ++j) {
            const int base_r = m0 + wr * 64 + i * 16;
            const int Cb     = n0 + wc * 64 + j * 16;
            const int rowg   = base_r + llo;
            const int colg   = Cb + lhi * 4;
            const size_t idx = (size_t)rowg * 2048 + colg;
            const size_t qx  = fmq(base_r, Cb, lhi, llo, 64) * 16 + (lhi & 1) * 8;
            f32x4 rp  = *(const f32x4*)(rpos + idx);
            bf16x4 db = *(const bf16x4*)(difff + qx);
            f32x4 o;
#pragma unroll
            for (int r = 0; r < 4; ++r)
                o[r] = 0.9f * rp[r] + 0.1f * fmaxf((float)db[r] - acc[i][j][r], 0.f);
            *(f32x4*)(outp + idx) = o;
            acc[i][j] = fzero;
        }
    }

    // ---- NEG part 1: rpv1/Wpeneg, 16 steps (step-0 loads already in flight) ----
    for (int it = 0; it < 8; ++it) {
        LD8(A1, B1, 1024)
        MFMA16(A0, B0, acc)
        ADV2
        if (it + 1 < 8) { LD8(A0, B0, 0) }
        MFMA16(A1, B1, acc)
    }
    // ---- NEG part 2: rsom/Wsomd, nks=8, 8 steps = 4 iters ----
    SETPA(rsomf, 8)
    SETPW(Wneg2f, 8, n0)
    LD8(A0, B0, 0)
    for (int it = 0; it < 4; ++it) {
        LD8(A1, B1, 1024)
        MFMA16(A0, B0, acc)
        ADV2
        if (it + 1 < 4) { LD8(A0, B0, 0) }
        MFMA16(A1, B1, acc)
    }

    // ---- NEG epilogue ----
#pragma unroll
    for (int i = 0; i < 4; ++i) {
#pragma unroll
        for (int j = 0; j < 4; ++j) {
            const int base_r = m0 + wr * 64 + i * 16;
            const int Cb     = n0 + wc * 64 + j * 16;
            const int rowg   = base_r + llo;
            const int colg   = Cb + lhi * 4;
            const size_t idx = (size_t)rowg * 2048 + colg;
            const size_t qx  = fmq(base_r, Cb, lhi, llo, 64) * 16 + (lhi & 1) * 8;
            f32x4 rn  = *(const f32x4*)(rneg + idx);
            bf16x4 db = *(const bf16x4*)(difff + qx);
            f32x4 o;
#pragma unroll
            for (int r = 0; r < 4; ++r)
                o[r] = 0.9f * rn[r] + 0.1f * fmaxf(-(float)db[r] - acc[i][j][r], 0.f);
            *(f32x4*)(outn + idx) = o;
        }
    }
}

extern "C" void kernel_launch(void* const* d_in, const int* in_sizes, int n_in,
                              void* d_out, int out_size, void* d_ws, size_t ws_size,
                              hipStream_t stream) {
    (void)in_sizes; (void)n_in; (void)out_size; (void)ws_size;

    const float* x       = (const float*)d_in[0];
    const float* ctx     = (const float*)d_in[1];
    const float* r_pos   = (const float*)d_in[2];
    const float* r_neg   = (const float*)d_in[3];
    const float* Wpred   = (const float*)d_in[4];
    const float* bpred   = (const float*)d_in[5];
    const float* Wpv1    = (const float*)d_in[6];
    const float* Wpv2    = (const float*)d_in[7];
    const float* Wvip    = (const float*)d_in[8];
    const float* Wsomin  = (const float*)d_in[9];
    const float* Wvipsom = (const float*)d_in[10];
    const float* Wpepos  = (const float*)d_in[11];
    const float* Wpeneg  = (const float*)d_in[12];
    const float* Wsomd   = (const float*)d_in[13];

    char* ws = (char*)d_ws;
    char* ctx_fm     = ws; ws += (size_t)BV * CTXV * 2;
    char* x_fm       = ws; ws += (size_t)BV * DIMV * 2;
    char* diff_fm    = ws; ws += (size_t)BV * DIMV * 2;
    char* rpv1_fm    = ws; ws += (size_t)BV * NPV * 2;
    char* rpv2_fm    = ws; ws += (size_t)BV * NPV * 2;
    char* rvip_fm    = ws; ws += (size_t)BV * NSV * 2;
    char* ssom_fm    = ws; ws += (size_t)BV * NSV * 2;
    char* rsom_fm    = ws; ws += (size_t)BV * NSV * 2;
    char* Wpred_fm   = ws; ws += (size_t)DIMV * CTXV * 2;
    char* WpredT_fm  = ws; ws += (size_t)CTXV * DIMV * 2;
    char* Wpv1_fm    = ws; ws += (size_t)NPV * DIMV * 2;
    char* Wpv2_fm    = ws; ws += (size_t)NPV * DIMV * 2;
    char* Wvip_fm    = ws; ws += (size_t)NSV * DIMV * 2;
    char* Wsomin_fm  = ws; ws += (size_t)NSV * DIMV * 2;
    char* Wvipsom_fm = ws; ws += (size_t)NSV * NSV * 2;
    char* Wpepos_fm  = ws; ws += (size_t)DIMV * NPV * 2;
    char* Wpeneg_fm  = ws; ws += (size_t)DIMV * NPV * 2;
    char* Wsomd_fm   = ws; ws += (size_t)DIMV * NSV * 2;
    char* Wcomb2_fm  = ws; ws += (size_t)NPV * CTXV * 2;
    char* Wcombv_fm  = ws; ws += (size_t)NSV * CTXV * 2;
    float* biascomb  = (float*)ws; ws += 768 * 4;

    float* out_pos = (float*)d_out;
    float* out_neg = out_pos + (size_t)BV * DIMV;

    // ---- FM conversions (12 jobs) ----
    FmArgs fa;
    auto setj = [&](int t, const float* s, char* dst, int lognks, int ld, int trans) {
        fa.j[t].src = s; fa.j[t].dst = dst; fa.j[t].lognks = lognks;
        fa.j[t].ld = ld; fa.j[t].trans = trans;
    };
    setj(0,  ctx,     ctx_fm,     4, 512,  0);
    setj(1,  x,       x_fm,       6, 2048, 0);
    setj(2,  Wpred,   Wpred_fm,   4, 512,  0);
    setj(3,  Wpred,   WpredT_fm,  6, 512,  1);   // WpredT[r][k] = Wpred[k][r]
    setj(4,  Wpv1,    Wpv1_fm,    6, 2048, 0);
    setj(5,  Wpv2,    Wpv2_fm,    6, 2048, 0);
    setj(6,  Wvip,    Wvip_fm,    6, 2048, 0);
    setj(7,  Wsomin,  Wsomin_fm,  6, 2048, 0);
    setj(8,  Wvipsom, Wvipsom_fm, 3, 256,  0);
    setj(9,  Wpepos,  Wpepos_fm,  4, 512,  0);
    setj(10, Wpeneg,  Wpeneg_fm,  4, 512,  0);
    setj(11, Wsomd,   Wsomd_fm,   3, 256,  0);
    const unsigned cum[13] = {0u, 524288u, 2621440u, 2752512u, 2883584u,
                              3014656u, 3145728u, 3211264u, 3276800u,
                              3284992u, 3416064u, 3547136u, 3612672u};
    for (int t = 0; t < 13; ++t) fa.cum[t] = cum[t];
    cvt_fm<<<dim3(2048), dim3(256), 0, stream>>>(fa);
    bias_comb<<<dim3(96), dim3(512), 0, stream>>>(Wpv2, Wvip, bpred, biascomb);

    const int BIG = 1 << 28;
    GemmDesc dz;
    dz.A = nullptr; dz.nksA = 1; dz.W1 = dz.W2 = nullptr; dz.nksW = 1;
    dz.NB1 = BIG; dz.ntN = 1; dz.nsteps = 2; dz.epi = 3;
    dz.bias = nullptr; dz.subp = nullptr; dz.nksSub = 1;
    dz.out1 = nullptr; dz.nksO1 = 1; dz.out2 = nullptr; dz.nksO2 = 1;

    // L2: diff = x - (ctx@Wpred^T + b) (1024 blocks) || Wcomb2 (16) || Wcombv (8)
    GemmDesc d_pred = dz;
    d_pred.A = ctx_fm; d_pred.nksA = 16;
    d_pred.W1 = Wpred_fm; d_pred.nksW = 16;
    d_pred.ntN = 16; d_pred.nsteps = 16; d_pred.epi = 0;
    d_pred.bias = bpred;
    d_pred.subp = x_fm; d_pred.nksSub = 64;
    d_pred.out1 = diff_fm; d_pred.nksO1 = 64;

    GemmDesc d_c2 = dz;
    d_c2.A = Wpv2_fm; d_c2.nksA = 64;
    d_c2.W1 = WpredT_fm; d_c2.nksW = 64;
    d_c2.ntN = 4; d_c2.nsteps = 64; d_c2.epi = 3;
    d_c2.out1 = Wcomb2_fm; d_c2.nksO1 = 16;

    GemmDesc d_cv = d_c2;
    d_cv.A = Wvip_fm;
    d_cv.out1 = Wcombv_fm; d_cv.nksO1 = 16;

    pe_gemm6<<<dim3(1048), dim3(256), 0, stream>>>(d_pred, d_c2, d_cv, 1024, 1040);

    // L3: 2+3 (384) || 4'+5' (384)
    GemmDesc d_23 = dz;
    d_23.A = x_fm; d_23.nksA = 64;
    d_23.W1 = Wpv1_fm; d_23.W2 = Wsomin_fm; d_23.nksW = 64;
    d_23.NB1 = NPV; d_23.ntN = 6; d_23.nsteps = 64; d_23.epi = 1;
    d_23.out1 = rpv1_fm; d_23.nksO1 = 16;
    d_23.out2 = ssom_fm; d_23.nksO2 = 8;

    GemmDesc d_45 = dz;
    d_45.A = ctx_fm; d_45.nksA = 16;
    d_45.W1 = Wcomb2_fm; d_45.W2 = Wcombv_fm; d_45.nksW = 16;
    d_45.NB1 = NPV; d_45.ntN = 6; d_45.nsteps = 16; d_45.epi = 4;
    d_45.bias = biascomb;
    d_45.out1 = rpv2_fm; d_45.nksO1 = 16;
    d_45.out2 = rvip_fm; d_45.nksO2 = 8;

    pe_gemm6<<<dim3(768), dim3(256), 0, stream>>>(d_23, d_45, dz, 384, 768);

    // L4: rsom = relu(ssom - rvip @ Wvipsom^T)  (128 blocks)
    GemmDesc d_som = dz;
    d_som.A = rvip_fm; d_som.nksA = 8;
    d_som.W1 = Wvipsom_fm; d_som.nksW = 8;
    d_som.ntN = 2; d_som.nsteps = 8; d_som.epi = 2;
    d_som.subp = ssom_fm; d_som.nksSub = 8;
    d_som.out1 = rsom_fm; d_som.nksO1 = 8;

    pe_gemm6<<<dim3(128), dim3(256), 0, stream>>>(d_som, d_som, d_som, 128, 128);

    // L5: merged FILT (1024 blocks)
    pe_filt6<<<dim3(1024), dim3(256), 0, stream>>>(
        rpv2_fm, Wpepos_fm, rpv1_fm, rsom_fm, Wpeneg_fm, Wsomd_fm,
        diff_fm, r_pos, r_neg, out_pos, out_neg);
}